// Round 6
// baseline (409.975 us; speedup 1.0000x reference)
//
#include <hip/hip_runtime.h>
#include <stdint.h>

typedef __attribute__((ext_vector_type(4))) float f32x4;
typedef __attribute__((ext_vector_type(8))) short short8;
typedef __attribute__((ext_vector_type(4))) short s16x4;

#define DEV __device__ __forceinline__

constexpr int Bc = 2, Sc = 2048, Dc = 2048, Hc = 16, HDc = 128;
constexpr int Mc = Bc * Sc;                        // 4096 rows
constexpr float ATTN_SCALE = 0.08838834764831843f; // 1/sqrt(128)

DEV short f2bf(float f) {                          // f32 -> bf16 (RNE)
  unsigned u = __float_as_uint(f);
  unsigned r = (u + 0x7fffu + ((u >> 16) & 1u)) >> 16;
  return (short)(unsigned short)r;
}

// global -> LDS direct copy, 16B per lane. LDS dest is wave-uniform base;
// HW adds lane*16. Global source may be per-lane.
DEV void gload_lds16(const void* gsrc, void* ldst) {
  typedef const __attribute__((address_space(1))) void as1_cvoid;
  typedef __attribute__((address_space(3))) void as3_void;
  __builtin_amdgcn_global_load_lds((as1_cvoid*)(uintptr_t)gsrc,
                                   (as3_void*)(uint32_t)(uintptr_t)ldst,
                                   16, 0, 0);
}

__global__ void cast_f32_bf16(const float* __restrict__ in, short* __restrict__ out, int n8) {
  int i = blockIdx.x * 256 + threadIdx.x;
  if (i >= n8) return;
  f32x4 a = ((const f32x4*)in)[i * 2];
  f32x4 b = ((const f32x4*)in)[i * 2 + 1];
  short8 o;
  o[0] = f2bf(a[0]); o[1] = f2bf(a[1]); o[2] = f2bf(a[2]); o[3] = f2bf(a[3]);
  o[4] = f2bf(b[0]); o[5] = f2bf(b[1]); o[6] = f2bf(b[2]); o[7] = f2bf(b[3]);
  ((short8*)out)[i] = o;
}

__global__ void rope_table(float* __restrict__ ct, float* __restrict__ st) {
  int t = blockIdx.x * 256 + threadIdx.x;   // [0, S*64)
  int s = t >> 6, i = t & 63;
  float freq = powf(10000.0f, -(float)(2 * i) * (1.0f / 128.0f));
  float a = (float)s * freq;
  float sv, cv;
  sincosf(a, &sv, &cv);
  ct[t] = cv; st[t] = sv;
}

// ---------------------------------------------------------------------------
// 8-phase 256x256 QKV GEMM (m201 structure, plain HIP).
// BK=64 split in 2 K-halves; LDS = 4 half-slots per operand (dbuf x Khalf),
// each [256 rows][32 K] bf16 = 16 KB. 8 waves (2M x 4N), wave tile 128x64.
// Per K-tile: 4 phases {reads, 1 half-tile stage, barrier, lgkm0, 16 MFMA,
// barrier}; counted vmcnt(6) once per tile (phase 4). Never drains mid-loop.
// Stage ledger: ph1(t)->A-K1[t+1], ph2(t)->B-K0[t+2], ph3(t)->A-K0[t+2],
// ph4(t)->B-K1[t+2]; each slot is dead one phase before its restage.
// Epilogue: RoPE+reshape store for q,k; transposed [B,H,HD,S] store for v.
// ---------------------------------------------------------------------------
__global__ __launch_bounds__(512, 2) void gemm8_qkv(
    const short* __restrict__ A,
    const short* __restrict__ Wq, const short* __restrict__ Wk, const short* __restrict__ Wv,
    short* __restrict__ qo, short* __restrict__ ko_, short* __restrict__ vo,
    const float* __restrict__ ct, const float* __restrict__ st) {
  constexpr int K = Dc, NT = K / 64;
  __shared__ short As[4][8192];   // 64 KB: slot = (db*2 + khalf), [256][32]
  __shared__ short Bs[4][8192];   // 64 KB

  const int tid = threadIdx.x, lane = tid & 63, w = tid >> 6;
  const int g = lane >> 4, c = lane & 15;
  const int wr = w >> 2, wc = w & 3;

  // bijective XCD swizzle (24*16 = 384 blocks, %8==0)
  const int nx = gridDim.x;
  const int nwg = nx * gridDim.y;
  const int flat = blockIdx.y * nx + blockIdx.x;
  const int swz = (flat & 7) * (nwg >> 3) + (flat >> 3);
  const int bx = swz % nx, by = swz / nx;

  const int m0 = by * 256;
  const int which = bx >> 3;                 // 0=q 1=k 2=v
  const int n0 = (bx & 7) * 256;             // col within D
  const short* Wm = (which == 0) ? Wq : (which == 1) ? Wk : Wv;

  const short* gA = A  + (size_t)(m0 + (tid >> 2)) * K + (tid & 3) * 8;
  const short* gB = Wm + (size_t)(n0 + (tid >> 2)) * K + (tid & 3) * 8;
  char* aW = (char*)As + w * 1024;
  char* bW = (char*)Bs + w * 1024;
  const char* aR = (const char*)As + (wr * 128 + c) * 64 + g * 16;
  const char* bR = (const char*)Bs + (wc * 64 + c) * 64 + g * 16;

#define STG8(ptr, dst, koff)                                        \
  do {                                                              \
    gload_lds16((ptr) + (koff), (dst));                             \
    gload_lds16((ptr) + (size_t)128 * K + (koff), (dst) + 8192);    \
  } while (0)

  f32x4 acc[8][4] = {};
  short8 Af[4], Bf[4];

  // prologue: tile 0 -> slots 0,1 ; tile 1 -> slots 2,3
  STG8(gA, aW + 0 * 16384, 0);
  STG8(gB, bW + 0 * 16384, 0);
  STG8(gA, aW + 1 * 16384, 32);
  STG8(gB, bW + 1 * 16384, 32);
  STG8(gA, aW + 2 * 16384, 64);
  STG8(gB, bW + 2 * 16384, 64);
  STG8(gA, aW + 3 * 16384, 96);
  STG8(gB, bW + 3 * 16384, 96);
  asm volatile("s_waitcnt vmcnt(8)" ::: "memory");   // tile 0 resident
  __builtin_amdgcn_sched_barrier(0);
  __builtin_amdgcn_s_barrier();
  __builtin_amdgcn_sched_barrier(0);

#define RDA(base)                                   \
  Af[0] = *(const short8*)((base));                 \
  Af[1] = *(const short8*)((base) + 1024);          \
  Af[2] = *(const short8*)((base) + 2048);          \
  Af[3] = *(const short8*)((base) + 3072)
#define RDB(base)                                   \
  Bf[0] = *(const short8*)((base));                 \
  Bf[1] = *(const short8*)((base) + 1024);          \
  Bf[2] = *(const short8*)((base) + 2048);          \
  Bf[3] = *(const short8*)((base) + 3072)
#define MM(mb)                                      \
  _Pragma("unroll")                                 \
  for (int mi = 0; mi < 4; ++mi)                    \
    _Pragma("unroll")                               \
    for (int nj = 0; nj < 4; ++nj)                  \
      acc[(mb) + mi][nj] = __builtin_amdgcn_mfma_f32_16x16x32_bf16(Af[mi], Bf[nj], acc[(mb) + mi][nj], 0, 0, 0)
#define SYNC_PRE()                                   \
  __builtin_amdgcn_s_barrier();                      \
  asm volatile("s_waitcnt lgkmcnt(0)" ::: "memory"); \
  __builtin_amdgcn_sched_barrier(0)
#define SYNC_POST()                                  \
  __builtin_amdgcn_s_barrier();                      \
  __builtin_amdgcn_sched_barrier(0)

  for (int t = 0; t < NT; ++t) {
    const int so = (t & 1) * 32768;      // dbuf byte offset (2 slots of 16 KB)
    // ---- phase 1: kk=0, rows 0-63. reads B-K0 + A-K0.lo; stage A-K1[t+1]
    RDB(bR + so);
    RDA(aR + so);
    if (t >= 1 && t + 1 < NT) STG8(gA, aW + (((t + 1) & 1) * 2 + 1) * 16384, (size_t)(t + 1) * 64 + 32);
    SYNC_PRE();
    __builtin_amdgcn_s_setprio(1);
    MM(0);
    __builtin_amdgcn_s_setprio(0);
    SYNC_POST();
    // ---- phase 2: kk=0, rows 64-127. reads A-K0.hi; stage B-K0[t+2]
    RDA(aR + so + 4096);
    if (t + 2 < NT) STG8(gB, bW + ((t & 1) * 2) * 16384, (size_t)(t + 2) * 64);
    SYNC_PRE();
    __builtin_amdgcn_s_setprio(1);
    MM(4);
    __builtin_amdgcn_s_setprio(0);
    SYNC_POST();
    // ---- phase 3: kk=1, rows 0-63. reads B-K1 + A-K1.lo; stage A-K0[t+2]
    RDB(bR + so + 16384);
    RDA(aR + so + 16384);
    if (t + 2 < NT) STG8(gA, aW + ((t & 1) * 2) * 16384, (size_t)(t + 2) * 64);
    SYNC_PRE();
    __builtin_amdgcn_s_setprio(1);
    MM(0);
    __builtin_amdgcn_s_setprio(0);
    SYNC_POST();
    // ---- phase 4: kk=1, rows 64-127. reads A-K1.hi; stage B-K1[t+2]; vmcnt
    RDA(aR + so + 16384 + 4096);
    if (t + 2 < NT) {
      STG8(gB, bW + ((t & 1) * 2 + 1) * 16384, (size_t)(t + 2) * 64 + 32);
      asm volatile("s_waitcnt vmcnt(6)" ::: "memory");   // confirms tile t+1
    } else {
      asm volatile("s_waitcnt vmcnt(0)" ::: "memory");
    }
    __builtin_amdgcn_sched_barrier(0);
    SYNC_PRE();
    __builtin_amdgcn_s_setprio(1);
    MM(4);
    __builtin_amdgcn_s_setprio(0);
    SYNC_POST();
  }
#undef STG8
#undef RDA
#undef RDB
#undef MM
#undef SYNC_PRE
#undef SYNC_POST

  if (which < 2) {
    short* outb = (which == 0) ? qo : ko_;
#pragma unroll
    for (int mi8 = 0; mi8 < 8; ++mi8)
#pragma unroll
      for (int nj = 0; nj < 4; ++nj)
#pragma unroll
        for (int r = 0; r < 4; ++r) {
          int row = m0 + wr * 128 + mi8 * 16 + g * 4 + r;
          int col = n0 + wc * 64 + nj * 16 + c;
          float v = acc[mi8][nj][r];
          float other = __shfl_xor(v, 1);
          int pi = (col & (HDc - 1)) >> 1;
          int sp = row & (Sc - 1);
          float cv = ct[sp * 64 + pi], sv = st[sp * 64 + pi];
          v = ((col & 1) == 0) ? (v * cv - other * sv) : (other * sv + v * cv);
          int b_ = row >> 11, sq = row & (Sc - 1);
          int h_ = col >> 7, dd = col & (HDc - 1);
          outb[((size_t)(b_ * Hc + h_) * Sc + sq) * HDc + dd] = f2bf(v);
        }
  } else {
    // V^T store: vo[b][h][dd][s]
#pragma unroll
    for (int mi8 = 0; mi8 < 8; ++mi8)
#pragma unroll
      for (int nj = 0; nj < 4; ++nj) {
        int row0 = m0 + wr * 128 + mi8 * 16 + g * 4;
        int col = n0 + wc * 64 + nj * 16 + c;
        int b_ = row0 >> 11, sq0 = row0 & (Sc - 1);
        int h_ = col >> 7, dd = col & (HDc - 1);
        s16x4 pk;
#pragma unroll
        for (int r = 0; r < 4; ++r) pk[r] = f2bf(acc[mi8][nj][r]);
        *(s16x4*)&vo[((size_t)(b_ * Hc + h_) * HDc + dd) * Sc + sq0] = pk;
      }
  }
}

// ---------------------------------------------------------------------------
// Out-projection NT-GEMM (round-5 structure, known good): BM=128, BN=256,
// BK=64, reg frag double-buffer, counted vmcnt(6), f32 output [M][D].
// ---------------------------------------------------------------------------
__global__ __launch_bounds__(512, 2) void gemm_pipe_out(
    const short* __restrict__ A, const short* __restrict__ W0,
    float* __restrict__ outf) {
  constexpr int K = Dc, NT = K / 64;
  __shared__ short As[2][128][64];       // 32 KB
  __shared__ short Bs[2][2][128][64];    // 64 KB

  const int tid = threadIdx.x, lane = tid & 63, w = tid >> 6;
  const int g = lane >> 4, c = lane & 15;
  const int wr = w >> 2, wc = w & 3;

  const int nx = gridDim.x;
  const int nwg = nx * gridDim.y;
  const int flat = blockIdx.y * nx + blockIdx.x;
  const int swz = (flat & 7) * (nwg >> 3) + (flat >> 3);
  const int nbx = swz % nx, nby = swz / nx;

  const int m0 = nby * 128;
  const int wn0 = nbx * 256;

  const int r1 = tid >> 3, p1 = tid & 7;
  const int psw = (p1 ^ (r1 & 7)) * 8;
  const short* gA0 = A + (size_t)(m0 + r1) * K + psw;
  const short* gA1 = gA0 + (size_t)64 * K;
  const short* gB0 = W0 + (size_t)(wn0 + r1) * K + psw;
  const short* gB1 = gB0 + (size_t)64 * K;
  const short* gB2 = gB0 + (size_t)128 * K;
  const short* gB3 = gB0 + (size_t)192 * K;
  char* ldsA = (char*)As + w * 1024;
  char* ldsB = (char*)Bs + w * 1024;

#define STAGE(t, db)                                        \
  do {                                                      \
    const size_t ko_ = (size_t)(t) * 64;                    \
    gload_lds16(gA0 + ko_, ldsA + (db) * 16384);            \
    gload_lds16(gA1 + ko_, ldsA + (db) * 16384 + 8192);     \
    gload_lds16(gB0 + ko_, ldsB + (db) * 32768);            \
    gload_lds16(gB1 + ko_, ldsB + (db) * 32768 + 8192);     \
    gload_lds16(gB2 + ko_, ldsB + (db) * 32768 + 16384);    \
    gload_lds16(gB3 + ko_, ldsB + (db) * 32768 + 24576);    \
  } while (0)

  f32x4 acc[4][4] = {};
  const int cx = (g ^ (c & 7)) * 16;
  const char* aBase = (const char*)As + (wr * 64 + c) * 128;
  const char* bBase = (const char*)Bs + (wc >> 1) * 16384 + ((wc & 1) * 64 + c) * 128;

  short8 afA[2][4], bfA[2][4], afB[2][4], bfB[2][4];

#define READ_FRAGS(af, bf, db)                                                        \
  do {                                                                                \
    const char* aB = aBase + (db) * 16384;                                            \
    const char* bB = bBase + (db) * 32768;                                            \
    _Pragma("unroll")                                                                 \
    for (int kk = 0; kk < 2; ++kk) {                                                  \
      const int co = cx ^ (kk * 64);                                                  \
      _Pragma("unroll")                                                               \
      for (int mi = 0; mi < 4; ++mi) af[kk][mi] = *(const short8*)(aB + mi * 2048 + co); \
      _Pragma("unroll")                                                               \
      for (int nj = 0; nj < 4; ++nj) bf[kk][nj] = *(const short8*)(bB + nj * 2048 + co); \
    }                                                                                 \
  } while (0)

#define MFMA_ALL(af, bf)                                                              \
  do {                                                                                \
    _Pragma("unroll")                                                                 \
    for (int kk = 0; kk < 2; ++kk)                                                    \
      _Pragma("unroll")                                                               \
      for (int mi = 0; mi < 4; ++mi)                                                  \
        _Pragma("unroll")                                                             \
        for (int nj = 0; nj < 4; ++nj)                                                \
          acc[mi][nj] = __builtin_amdgcn_mfma_f32_16x16x32_bf16(af[kk][mi], bf[kk][nj], acc[mi][nj], 0, 0, 0); \
  } while (0)

  STAGE(0, 0);
  STAGE(1, 1);
  asm volatile("s_waitcnt vmcnt(6)" ::: "memory");
  __builtin_amdgcn_sched_barrier(0);
  __builtin_amdgcn_s_barrier();
  READ_FRAGS(afA, bfA, 0);
  asm volatile("s_waitcnt lgkmcnt(0)" ::: "memory");
  __builtin_amdgcn_sched_barrier(0);
  __builtin_amdgcn_s_barrier();

  for (int t = 0; t < NT; t += 2) {
    if (t + 2 < NT) { STAGE(t + 2, 0); asm volatile("s_waitcnt vmcnt(6)" ::: "memory"); }
    else            { asm volatile("s_waitcnt vmcnt(0)" ::: "memory"); }
    __builtin_amdgcn_sched_barrier(0);
    __builtin_amdgcn_s_barrier();
    READ_FRAGS(afB, bfB, 1);
    __builtin_amdgcn_sched_barrier(0);
    __builtin_amdgcn_s_setprio(1);
    MFMA_ALL(afA, bfA);
    __builtin_amdgcn_s_setprio(0);
    asm volatile("s_waitcnt lgkmcnt(0)" ::: "memory");
    __builtin_amdgcn_sched_barrier(0);
    __builtin_amdgcn_s_barrier();

    if (t + 3 < NT) { STAGE(t + 3, 1); asm volatile("s_waitcnt vmcnt(6)" ::: "memory"); }
    else            { asm volatile("s_waitcnt vmcnt(0)" ::: "memory"); }
    __builtin_amdgcn_sched_barrier(0);
    __builtin_amdgcn_s_barrier();
    if (t + 2 < NT) READ_FRAGS(afA, bfA, 0);
    __builtin_amdgcn_sched_barrier(0);
    __builtin_amdgcn_s_setprio(1);
    MFMA_ALL(afB, bfB);
    __builtin_amdgcn_s_setprio(0);
    asm volatile("s_waitcnt lgkmcnt(0)" ::: "memory");
    __builtin_amdgcn_sched_barrier(0);
    __builtin_amdgcn_s_barrier();
  }
#undef STAGE
#undef READ_FRAGS
#undef MFMA_ALL

#pragma unroll
  for (int mi = 0; mi < 4; ++mi)
#pragma unroll
    for (int nj = 0; nj < 4; ++nj)
#pragma unroll
      for (int r = 0; r < 4; ++r) {
        int row = m0 + wr * 64 + mi * 16 + g * 4 + r;
        int col = wn0 + wc * 64 + nj * 16 + c;
        outf[(size_t)row * Dc + col] = acc[mi][nj][r];
      }
}

// ---------------------------------------------------------------------------
// Flash causal attention (unchanged). 4 waves; Q-tile 64, KV 64.
// ---------------------------------------------------------------------------
DEV void stage_kv(const short* kh, const short* vth, int kv0,
                  short* Kb, short* Vb, int w, int tid) {
#pragma unroll
  for (int i = 0; i < 4; ++i) {                 // K: 1024 chunks, 16/row
    int L = i * 256 + tid;
    int row = L >> 4, p = L & 15;
    gload_lds16(kh + (size_t)(kv0 + row) * HDc + ((p ^ (row & 7)) * 8),
                (char*)Kb + i * 4096 + w * 1024);
  }
#pragma unroll
  for (int i = 0; i < 4; ++i) {                 // V^T: 1024 chunks, 8/row
    int L = i * 256 + tid;
    int row = L >> 3, p = L & 7;
    gload_lds16(vth + (size_t)row * Sc + kv0 + ((p ^ (row & 7)) * 8),
                (char*)Vb + i * 4096 + w * 1024);
  }
}

__global__ __launch_bounds__(256) void attn_kernel(
    const short* __restrict__ qb, const short* __restrict__ kb,
    const short* __restrict__ vtb, short* __restrict__ ob) {
  __shared__ short Kl[2][64 * 128];
  __shared__ short Vl[2][128 * 64];
  __shared__ short Pl[4 * 16 * 72];

  const int tid = threadIdx.x, lane = tid & 63, w = tid >> 6;
  const int g = lane >> 4, c = lane & 15;
  const int bh = blockIdx.y;
  const int b_ = bh >> 4, h_ = bh & 15;
  const short* qh = qb + (size_t)bh * Sc * HDc;
  const short* kh = kb + (size_t)bh * Sc * HDc;
  const short* vth = vtb + (size_t)bh * HDc * Sc;

  for (int pass = 0; pass < 2; ++pass) {
    const int qt = pass ? (31 - blockIdx.x) : blockIdx.x;
    const int q0 = qt * 64;

    short8 qf[4];
#pragma unroll
    for (int kc = 0; kc < 4; ++kc)
      qf[kc] = *(const short8*)&qh[(size_t)(q0 + w * 16 + c) * HDc + kc * 32 + g * 8];

    float mrow[4], lrow[4];
    f32x4 acc[8] = {};
#pragma unroll
    for (int r = 0; r < 4; ++r) { mrow[r] = -1e30f; lrow[r] = 0.f; }

    const int nt = qt + 1;
    int cur = 0;
    stage_kv(kh, vth, 0, Kl[0], Vl[0], w, tid);
    __syncthreads();

    for (int kvt = 0; kvt < nt; ++kvt) {
      if (kvt + 1 < nt)
        stage_kv(kh, vth, (kvt + 1) * 64, Kl[cur ^ 1], Vl[cur ^ 1], w, tid);

      f32x4 sacc[4];
#pragma unroll
      for (int kb_ = 0; kb_ < 4; ++kb_) {
        sacc[kb_] = (f32x4){0.f, 0.f, 0.f, 0.f};
#pragma unroll
        for (int kc = 0; kc < 4; ++kc) {
          short8 kf = *(const short8*)&Kl[cur][(kb_ * 16 + c) * 128 + (((kc * 4 + g) ^ (c & 7)) * 8)];
          sacc[kb_] = __builtin_amdgcn_mfma_f32_16x16x32_bf16(qf[kc], kf, sacc[kb_], 0, 0, 0);
        }
      }
      float p[4][4];
      const bool last = (kvt == qt);
      const int kv0 = kvt * 64;
#pragma unroll
      for (int kb_ = 0; kb_ < 4; ++kb_)
#pragma unroll
        for (int r = 0; r < 4; ++r) {
          float s = sacc[kb_][r] * ATTN_SCALE;
          if (last) {
            int qg = q0 + w * 16 + g * 4 + r;
            int kg = kv0 + kb_ * 16 + c;
            if (kg > qg) s = -1e30f;
          }
          p[kb_][r] = s;
        }
      float scal[4];
#pragma unroll
      for (int r = 0; r < 4; ++r) {
        float v = fmaxf(fmaxf(p[0][r], p[1][r]), fmaxf(p[2][r], p[3][r]));
        v = fmaxf(v, __shfl_xor(v, 1));
        v = fmaxf(v, __shfl_xor(v, 2));
        v = fmaxf(v, __shfl_xor(v, 4));
        v = fmaxf(v, __shfl_xor(v, 8));
        float mn = fmaxf(mrow[r], v);
        scal[r] = __expf(mrow[r] - mn);
        mrow[r] = mn;
      }
#pragma unroll
      for (int r = 0; r < 4; ++r) {
        float acc_s = 0.f;
#pragma unroll
        for (int kb_ = 0; kb_ < 4; ++kb_) {
          p[kb_][r] = __expf(p[kb_][r] - mrow[r]);
          acc_s += p[kb_][r];
        }
        acc_s += __shfl_xor(acc_s, 1);
        acc_s += __shfl_xor(acc_s, 2);
        acc_s += __shfl_xor(acc_s, 4);
        acc_s += __shfl_xor(acc_s, 8);
        lrow[r] = lrow[r] * scal[r] + acc_s;
      }
#pragma unroll
      for (int db = 0; db < 8; ++db)
#pragma unroll
        for (int r = 0; r < 4; ++r) acc[db][r] *= scal[r];
#pragma unroll
      for (int kb_ = 0; kb_ < 4; ++kb_)
#pragma unroll
        for (int r = 0; r < 4; ++r)
          Pl[w * 16 * 72 + (g * 4 + r) * 72 + kb_ * 16 + c] = f2bf(p[kb_][r]);
      short8 pa[2];
#pragma unroll
      for (int k2 = 0; k2 < 2; ++k2)
        pa[k2] = *(const short8*)&Pl[w * 16 * 72 + c * 72 + k2 * 32 + g * 8];
#pragma unroll
      for (int db = 0; db < 8; ++db)
#pragma unroll
        for (int k2 = 0; k2 < 2; ++k2) {
          short8 vf = *(const short8*)&Vl[cur][(db * 16 + c) * 64 + (((k2 * 4 + g) ^ (c & 7)) * 8)];
          acc[db] = __builtin_amdgcn_mfma_f32_16x16x32_bf16(pa[k2], vf, acc[db], 0, 0, 0);
        }
      __syncthreads();
      cur ^= 1;
    }

#pragma unroll
    for (int db = 0; db < 8; ++db)
#pragma unroll
      for (int r = 0; r < 4; ++r) {
        int qg = q0 + w * 16 + g * 4 + r;
        int d = db * 16 + c;
        float v = acc[db][r] / lrow[r];
        ob[((size_t)(b_ * Sc + qg)) * Dc + h_ * HDc + d] = f2bf(v);
      }
  }
}

extern "C" void kernel_launch(void* const* d_in, const int* in_sizes, int n_in,
                              void* d_out, int out_size, void* d_ws, size_t ws_size,
                              hipStream_t stream) {
  const float* x = (const float*)d_in[0];
  const float* wq = (const float*)d_in[1];
  const float* wk = (const float*)d_in[2];
  const float* wv = (const float*)d_in[3];
  const float* wo = (const float*)d_in[4];
  float* out = (float*)d_out;

  char* ws = (char*)d_ws;
  short* xb  = (short*)(ws + 0);              // [4096][2048] bf16 (reused as attn-out)
  short* wqb = (short*)(ws + 16777216);
  short* wkb = (short*)(ws + 25165824);
  short* wvb = (short*)(ws + 33554432);
  short* wob = (short*)(ws + 41943040);
  short* qb  = (short*)(ws + 50331648);       // [B,H,S,HD]
  short* kbf = (short*)(ws + 67108864);       // [B,H,S,HD]
  short* vtb = (short*)(ws + 83886080);       // [B,H,HD,S]  (transposed V)
  float* ct  = (float*)(ws + 100663296);      // [S][64]
  float* st  = (float*)(ws + 101187584);
  short* obuf = xb;                           // reuse x buffer for attention output

  cast_f32_bf16<<<Mc * Dc / 8 / 256, 256, 0, stream>>>(x, xb, Mc * Dc / 8);
  cast_f32_bf16<<<Dc * Dc / 8 / 256, 256, 0, stream>>>(wq, wqb, Dc * Dc / 8);
  cast_f32_bf16<<<Dc * Dc / 8 / 256, 256, 0, stream>>>(wk, wkb, Dc * Dc / 8);
  cast_f32_bf16<<<Dc * Dc / 8 / 256, 256, 0, stream>>>(wv, wvb, Dc * Dc / 8);
  cast_f32_bf16<<<Dc * Dc / 8 / 256, 256, 0, stream>>>(wo, wob, Dc * Dc / 8);
  rope_table<<<Sc * 64 / 256, 256, 0, stream>>>(ct, st);

  // QKV: N' = 3*2048 over BN=256 -> 24 x-blocks; M=4096 over BM=256 -> 16 y-blocks
  gemm8_qkv<<<dim3(24, 16), 512, 0, stream>>>(xb, wqb, wkb, wvb, qb, kbf, vtb, ct, st);

  attn_kernel<<<dim3(Sc / 128, Bc * Hc), 256, 0, stream>>>(qb, kbf, vtb, obuf);

  // Out-proj: N = 2048 -> 8 x-blocks, M -> 32 y-blocks (256 blocks, full util)
  gemm_pipe_out<<<dim3(8, 32), 512, 0, stream>>>(obuf, wob, out);
}

// Round 7
// 409.967 us; speedup vs baseline: 1.0000x; 1.0000x over previous
//
#include <hip/hip_runtime.h>
#include <stdint.h>

typedef __attribute__((ext_vector_type(4))) float f32x4;
typedef __attribute__((ext_vector_type(8))) short short8;
typedef __attribute__((ext_vector_type(4))) short s16x4;

#define DEV __device__ __forceinline__

constexpr int Bc = 2, Sc = 2048, Dc = 2048, Hc = 16, HDc = 128;
constexpr int Mc = Bc * Sc;                        // 4096 rows
constexpr float ATTN_SCALE = 0.08838834764831843f; // 1/sqrt(128)

DEV short f2bf(float f) {                          // f32 -> bf16 (RNE)
  unsigned u = __float_as_uint(f);
  unsigned r = (u + 0x7fffu + ((u >> 16) & 1u)) >> 16;
  return (short)(unsigned short)r;
}

// global -> LDS direct copy, 16B per lane. LDS dest is wave-uniform base;
// HW adds lane*16. Global source may be per-lane.
DEV void gload_lds16(const void* gsrc, void* ldst) {
  typedef const __attribute__((address_space(1))) void as1_cvoid;
  typedef __attribute__((address_space(3))) void as3_void;
  __builtin_amdgcn_global_load_lds((as1_cvoid*)(uintptr_t)gsrc,
                                   (as3_void*)(uint32_t)(uintptr_t)ldst,
                                   16, 0, 0);
}

__global__ void cast_f32_bf16(const float* __restrict__ in, short* __restrict__ out, int n8) {
  int i = blockIdx.x * 256 + threadIdx.x;
  if (i >= n8) return;
  f32x4 a = ((const f32x4*)in)[i * 2];
  f32x4 b = ((const f32x4*)in)[i * 2 + 1];
  short8 o;
  o[0] = f2bf(a[0]); o[1] = f2bf(a[1]); o[2] = f2bf(a[2]); o[3] = f2bf(a[3]);
  o[4] = f2bf(b[0]); o[5] = f2bf(b[1]); o[6] = f2bf(b[2]); o[7] = f2bf(b[3]);
  ((short8*)out)[i] = o;
}

__global__ void rope_table(float* __restrict__ ct, float* __restrict__ st) {
  int t = blockIdx.x * 256 + threadIdx.x;   // [0, S*64)
  int s = t >> 6, i = t & 63;
  float freq = powf(10000.0f, -(float)(2 * i) * (1.0f / 128.0f));
  float a = (float)s * freq;
  float sv, cv;
  sincosf(a, &sv, &cv);
  ct[t] = cv; st[t] = sv;
}

// ---------------------------------------------------------------------------
// 8-phase 256x256 QKV GEMM (m201 structure) + T2 chunk swizzle.
// Slot layout [256 rows][32 K] bf16 (64 B/row, 4 chunks of 16 B). Swizzle:
// phys_chunk = chunk ^ ((row>>1)&3). Read side: lane(g,c) reads chunk
// g^((c>>1)&3) (constant per lane). Write side: global_load_lds is linear,
// so the per-thread GLOBAL source chunk is (tid&3)^((tid>>3)&3) -- the same
// involution; rows r and r+128 share it, so both STG8 gloads use one base.
// Bank spread: 8 consecutive rows cover all 8 bank-quads -> only free 2-way.
// Stage ledger: ph1(t)->A-K1[t+1], ph2(t)->B-K0[t+2], ph3(t)->A-K0[t+2],
// ph4(t)->B-K1[t+2]; vmcnt(6) once per tile (phase 4), never drains mid-loop.
// ---------------------------------------------------------------------------
__global__ __launch_bounds__(512, 2) void gemm8_qkv(
    const short* __restrict__ A,
    const short* __restrict__ Wq, const short* __restrict__ Wk, const short* __restrict__ Wv,
    short* __restrict__ qo, short* __restrict__ ko_, short* __restrict__ vo,
    const float* __restrict__ ct, const float* __restrict__ st) {
  constexpr int K = Dc, NT = K / 64;
  __shared__ short As[4][8192];   // 64 KB: slot = (db*2 + khalf), [256][32]
  __shared__ short Bs[4][8192];   // 64 KB

  const int tid = threadIdx.x, lane = tid & 63, w = tid >> 6;
  const int g = lane >> 4, c = lane & 15;
  const int wr = w >> 2, wc = w & 3;

  // bijective XCD swizzle (24*16 = 384 blocks, %8==0)
  const int nx = gridDim.x;
  const int nwg = nx * gridDim.y;
  const int flat = blockIdx.y * nx + blockIdx.x;
  const int swz = (flat & 7) * (nwg >> 3) + (flat >> 3);
  const int bx = swz % nx, by = swz / nx;

  const int m0 = by * 256;
  const int which = bx >> 3;                 // 0=q 1=k 2=v
  const int n0 = (bx & 7) * 256;             // col within D
  const short* Wm = (which == 0) ? Wq : (which == 1) ? Wk : Wv;

  // T2 swizzle: source chunk permuted so linear LDS write lands swizzled
  const int schunk = ((tid & 3) ^ ((tid >> 3) & 3)) * 8;
  const short* gA = A  + (size_t)(m0 + (tid >> 2)) * K + schunk;
  const short* gB = Wm + (size_t)(n0 + (tid >> 2)) * K + schunk;
  char* aW = (char*)As + w * 1024;
  char* bW = (char*)Bs + w * 1024;
  // read side: phys chunk = g ^ ((row>>1)&3), and (row>>1)&3 == (c>>1)&3
  const int rchunk = (g ^ ((c >> 1) & 3)) * 16;
  const char* aR = (const char*)As + (wr * 128 + c) * 64 + rchunk;
  const char* bR = (const char*)Bs + (wc * 64 + c) * 64 + rchunk;

#define STG8(ptr, dst, koff)                                        \
  do {                                                              \
    gload_lds16((ptr) + (koff), (dst));                             \
    gload_lds16((ptr) + (size_t)128 * K + (koff), (dst) + 8192);    \
  } while (0)

  f32x4 acc[8][4] = {};
  short8 Af[4], Bf[4];

  // prologue: tile 0 -> slots 0,1 ; tile 1 -> slots 2,3
  STG8(gA, aW + 0 * 16384, 0);
  STG8(gB, bW + 0 * 16384, 0);
  STG8(gA, aW + 1 * 16384, 32);
  STG8(gB, bW + 1 * 16384, 32);
  STG8(gA, aW + 2 * 16384, 64);
  STG8(gB, bW + 2 * 16384, 64);
  STG8(gA, aW + 3 * 16384, 96);
  STG8(gB, bW + 3 * 16384, 96);
  asm volatile("s_waitcnt vmcnt(8)" ::: "memory");   // tile 0 resident
  __builtin_amdgcn_sched_barrier(0);
  __builtin_amdgcn_s_barrier();
  __builtin_amdgcn_sched_barrier(0);

#define RDA(base)                                   \
  Af[0] = *(const short8*)((base));                 \
  Af[1] = *(const short8*)((base) + 1024);          \
  Af[2] = *(const short8*)((base) + 2048);          \
  Af[3] = *(const short8*)((base) + 3072)
#define RDB(base)                                   \
  Bf[0] = *(const short8*)((base));                 \
  Bf[1] = *(const short8*)((base) + 1024);          \
  Bf[2] = *(const short8*)((base) + 2048);          \
  Bf[3] = *(const short8*)((base) + 3072)
#define MM(mb)                                      \
  _Pragma("unroll")                                 \
  for (int mi = 0; mi < 4; ++mi)                    \
    _Pragma("unroll")                               \
    for (int nj = 0; nj < 4; ++nj)                  \
      acc[(mb) + mi][nj] = __builtin_amdgcn_mfma_f32_16x16x32_bf16(Af[mi], Bf[nj], acc[(mb) + mi][nj], 0, 0, 0)
#define SYNC_PRE()                                   \
  __builtin_amdgcn_s_barrier();                      \
  asm volatile("s_waitcnt lgkmcnt(0)" ::: "memory"); \
  __builtin_amdgcn_sched_barrier(0)
#define SYNC_POST()                                  \
  __builtin_amdgcn_s_barrier();                      \
  __builtin_amdgcn_sched_barrier(0)

  for (int t = 0; t < NT; ++t) {
    const int so = (t & 1) * 32768;      // dbuf byte offset (2 slots of 16 KB)
    // ---- phase 1: kk=0, rows 0-63. reads B-K0 + A-K0.lo; stage A-K1[t+1]
    RDB(bR + so);
    RDA(aR + so);
    if (t >= 1 && t + 1 < NT) STG8(gA, aW + (((t + 1) & 1) * 2 + 1) * 16384, (size_t)(t + 1) * 64 + 32);
    SYNC_PRE();
    __builtin_amdgcn_s_setprio(1);
    MM(0);
    __builtin_amdgcn_s_setprio(0);
    SYNC_POST();
    // ---- phase 2: kk=0, rows 64-127. reads A-K0.hi; stage B-K0[t+2]
    RDA(aR + so + 4096);
    if (t + 2 < NT) STG8(gB, bW + ((t & 1) * 2) * 16384, (size_t)(t + 2) * 64);
    SYNC_PRE();
    __builtin_amdgcn_s_setprio(1);
    MM(4);
    __builtin_amdgcn_s_setprio(0);
    SYNC_POST();
    // ---- phase 3: kk=1, rows 0-63. reads B-K1 + A-K1.lo; stage A-K0[t+2]
    RDB(bR + so + 16384);
    RDA(aR + so + 16384);
    if (t + 2 < NT) STG8(gA, aW + ((t & 1) * 2) * 16384, (size_t)(t + 2) * 64);
    SYNC_PRE();
    __builtin_amdgcn_s_setprio(1);
    MM(0);
    __builtin_amdgcn_s_setprio(0);
    SYNC_POST();
    // ---- phase 4: kk=1, rows 64-127. reads A-K1.hi; stage B-K1[t+2]; vmcnt
    RDA(aR + so + 16384 + 4096);
    if (t + 2 < NT) {
      STG8(gB, bW + ((t & 1) * 2 + 1) * 16384, (size_t)(t + 2) * 64 + 32);
      asm volatile("s_waitcnt vmcnt(6)" ::: "memory");   // confirms tile t+1
    } else {
      asm volatile("s_waitcnt vmcnt(0)" ::: "memory");
    }
    __builtin_amdgcn_sched_barrier(0);
    SYNC_PRE();
    __builtin_amdgcn_s_setprio(1);
    MM(4);
    __builtin_amdgcn_s_setprio(0);
    SYNC_POST();
  }
#undef STG8
#undef RDA
#undef RDB
#undef MM
#undef SYNC_PRE
#undef SYNC_POST

  if (which < 2) {
    short* outb = (which == 0) ? qo : ko_;
#pragma unroll
    for (int mi8 = 0; mi8 < 8; ++mi8)
#pragma unroll
      for (int nj = 0; nj < 4; ++nj)
#pragma unroll
        for (int r = 0; r < 4; ++r) {
          int row = m0 + wr * 128 + mi8 * 16 + g * 4 + r;
          int col = n0 + wc * 64 + nj * 16 + c;
          float v = acc[mi8][nj][r];
          float other = __shfl_xor(v, 1);
          int pi = (col & (HDc - 1)) >> 1;
          int sp = row & (Sc - 1);
          float cv = ct[sp * 64 + pi], sv = st[sp * 64 + pi];
          v = ((col & 1) == 0) ? (v * cv - other * sv) : (other * sv + v * cv);
          int b_ = row >> 11, sq = row & (Sc - 1);
          int h_ = col >> 7, dd = col & (HDc - 1);
          outb[((size_t)(b_ * Hc + h_) * Sc + sq) * HDc + dd] = f2bf(v);
        }
  } else {
    // V^T store: vo[b][h][dd][s]
#pragma unroll
    for (int mi8 = 0; mi8 < 8; ++mi8)
#pragma unroll
      for (int nj = 0; nj < 4; ++nj) {
        int row0 = m0 + wr * 128 + mi8 * 16 + g * 4;
        int col = n0 + wc * 64 + nj * 16 + c;
        int b_ = row0 >> 11, sq0 = row0 & (Sc - 1);
        int h_ = col >> 7, dd = col & (HDc - 1);
        s16x4 pk;
#pragma unroll
        for (int r = 0; r < 4; ++r) pk[r] = f2bf(acc[mi8][nj][r]);
        *(s16x4*)&vo[((size_t)(b_ * Hc + h_) * HDc + dd) * Sc + sq0] = pk;
      }
  }
}

// ---------------------------------------------------------------------------
// Out-projection NT-GEMM (round-5 structure, known good): BM=128, BN=256,
// BK=64, reg frag double-buffer, counted vmcnt(6), f32 output [M][D].
// ---------------------------------------------------------------------------
__global__ __launch_bounds__(512, 2) void gemm_pipe_out(
    const short* __restrict__ A, const short* __restrict__ W0,
    float* __restrict__ outf) {
  constexpr int K = Dc, NT = K / 64;
  __shared__ short As[2][128][64];       // 32 KB
  __shared__ short Bs[2][2][128][64];    // 64 KB

  const int tid = threadIdx.x, lane = tid & 63, w = tid >> 6;
  const int g = lane >> 4, c = lane & 15;
  const int wr = w >> 2, wc = w & 3;

  const int nx = gridDim.x;
  const int nwg = nx * gridDim.y;
  const int flat = blockIdx.y * nx + blockIdx.x;
  const int swz = (flat & 7) * (nwg >> 3) + (flat >> 3);
  const int nbx = swz % nx, nby = swz / nx;

  const int m0 = nby * 128;
  const int wn0 = nbx * 256;

  const int r1 = tid >> 3, p1 = tid & 7;
  const int psw = (p1 ^ (r1 & 7)) * 8;
  const short* gA0 = A + (size_t)(m0 + r1) * K + psw;
  const short* gA1 = gA0 + (size_t)64 * K;
  const short* gB0 = W0 + (size_t)(wn0 + r1) * K + psw;
  const short* gB1 = gB0 + (size_t)64 * K;
  const short* gB2 = gB0 + (size_t)128 * K;
  const short* gB3 = gB0 + (size_t)192 * K;
  char* ldsA = (char*)As + w * 1024;
  char* ldsB = (char*)Bs + w * 1024;

#define STAGE(t, db)                                        \
  do {                                                      \
    const size_t ko_ = (size_t)(t) * 64;                    \
    gload_lds16(gA0 + ko_, ldsA + (db) * 16384);            \
    gload_lds16(gA1 + ko_, ldsA + (db) * 16384 + 8192);     \
    gload_lds16(gB0 + ko_, ldsB + (db) * 32768);            \
    gload_lds16(gB1 + ko_, ldsB + (db) * 32768 + 8192);     \
    gload_lds16(gB2 + ko_, ldsB + (db) * 32768 + 16384);    \
    gload_lds16(gB3 + ko_, ldsB + (db) * 32768 + 24576);    \
  } while (0)

  f32x4 acc[4][4] = {};
  const int cx = (g ^ (c & 7)) * 16;
  const char* aBase = (const char*)As + (wr * 64 + c) * 128;
  const char* bBase = (const char*)Bs + (wc >> 1) * 16384 + ((wc & 1) * 64 + c) * 128;

  short8 afA[2][4], bfA[2][4], afB[2][4], bfB[2][4];

#define READ_FRAGS(af, bf, db)                                                        \
  do {                                                                                \
    const char* aB = aBase + (db) * 16384;                                            \
    const char* bB = bBase + (db) * 32768;                                            \
    _Pragma("unroll")                                                                 \
    for (int kk = 0; kk < 2; ++kk) {                                                  \
      const int co = cx ^ (kk * 64);                                                  \
      _Pragma("unroll")                                                               \
      for (int mi = 0; mi < 4; ++mi) af[kk][mi] = *(const short8*)(aB + mi * 2048 + co); \
      _Pragma("unroll")                                                               \
      for (int nj = 0; nj < 4; ++nj) bf[kk][nj] = *(const short8*)(bB + nj * 2048 + co); \
    }                                                                                 \
  } while (0)

#define MFMA_ALL(af, bf)                                                              \
  do {                                                                                \
    _Pragma("unroll")                                                                 \
    for (int kk = 0; kk < 2; ++kk)                                                    \
      _Pragma("unroll")                                                               \
      for (int mi = 0; mi < 4; ++mi)                                                  \
        _Pragma("unroll")                                                             \
        for (int nj = 0; nj < 4; ++nj)                                                \
          acc[mi][nj] = __builtin_amdgcn_mfma_f32_16x16x32_bf16(af[kk][mi], bf[kk][nj], acc[mi][nj], 0, 0, 0); \
  } while (0)

  STAGE(0, 0);
  STAGE(1, 1);
  asm volatile("s_waitcnt vmcnt(6)" ::: "memory");
  __builtin_amdgcn_sched_barrier(0);
  __builtin_amdgcn_s_barrier();
  READ_FRAGS(afA, bfA, 0);
  asm volatile("s_waitcnt lgkmcnt(0)" ::: "memory");
  __builtin_amdgcn_sched_barrier(0);
  __builtin_amdgcn_s_barrier();

  for (int t = 0; t < NT; t += 2) {
    if (t + 2 < NT) { STAGE(t + 2, 0); asm volatile("s_waitcnt vmcnt(6)" ::: "memory"); }
    else            { asm volatile("s_waitcnt vmcnt(0)" ::: "memory"); }
    __builtin_amdgcn_sched_barrier(0);
    __builtin_amdgcn_s_barrier();
    READ_FRAGS(afB, bfB, 1);
    __builtin_amdgcn_sched_barrier(0);
    __builtin_amdgcn_s_setprio(1);
    MFMA_ALL(afA, bfA);
    __builtin_amdgcn_s_setprio(0);
    asm volatile("s_waitcnt lgkmcnt(0)" ::: "memory");
    __builtin_amdgcn_sched_barrier(0);
    __builtin_amdgcn_s_barrier();

    if (t + 3 < NT) { STAGE(t + 3, 1); asm volatile("s_waitcnt vmcnt(6)" ::: "memory"); }
    else            { asm volatile("s_waitcnt vmcnt(0)" ::: "memory"); }
    __builtin_amdgcn_sched_barrier(0);
    __builtin_amdgcn_s_barrier();
    if (t + 2 < NT) READ_FRAGS(afA, bfA, 0);
    __builtin_amdgcn_sched_barrier(0);
    __builtin_amdgcn_s_setprio(1);
    MFMA_ALL(afB, bfB);
    __builtin_amdgcn_s_setprio(0);
    asm volatile("s_waitcnt lgkmcnt(0)" ::: "memory");
    __builtin_amdgcn_sched_barrier(0);
    __builtin_amdgcn_s_barrier();
  }
#undef STAGE
#undef READ_FRAGS
#undef MFMA_ALL

#pragma unroll
  for (int mi = 0; mi < 4; ++mi)
#pragma unroll
    for (int nj = 0; nj < 4; ++nj)
#pragma unroll
      for (int r = 0; r < 4; ++r) {
        int row = m0 + wr * 64 + mi * 16 + g * 4 + r;
        int col = wn0 + wc * 64 + nj * 16 + c;
        outf[(size_t)row * Dc + col] = acc[mi][nj][r];
      }
}

// ---------------------------------------------------------------------------
// Flash causal attention (unchanged). 4 waves; Q-tile 64, KV 64.
// ---------------------------------------------------------------------------
DEV void stage_kv(const short* kh, const short* vth, int kv0,
                  short* Kb, short* Vb, int w, int tid) {
#pragma unroll
  for (int i = 0; i < 4; ++i) {                 // K: 1024 chunks, 16/row
    int L = i * 256 + tid;
    int row = L >> 4, p = L & 15;
    gload_lds16(kh + (size_t)(kv0 + row) * HDc + ((p ^ (row & 7)) * 8),
                (char*)Kb + i * 4096 + w * 1024);
  }
#pragma unroll
  for (int i = 0; i < 4; ++i) {                 // V^T: 1024 chunks, 8/row
    int L = i * 256 + tid;
    int row = L >> 3, p = L & 7;
    gload_lds16(vth + (size_t)row * Sc + kv0 + ((p ^ (row & 7)) * 8),
                (char*)Vb + i * 4096 + w * 1024);
  }
}

__global__ __launch_bounds__(256) void attn_kernel(
    const short* __restrict__ qb, const short* __restrict__ kb,
    const short* __restrict__ vtb, short* __restrict__ ob) {
  __shared__ short Kl[2][64 * 128];
  __shared__ short Vl[2][128 * 64];
  __shared__ short Pl[4 * 16 * 72];

  const int tid = threadIdx.x, lane = tid & 63, w = tid >> 6;
  const int g = lane >> 4, c = lane & 15;
  const int bh = blockIdx.y;
  const int b_ = bh >> 4, h_ = bh & 15;
  const short* qh = qb + (size_t)bh * Sc * HDc;
  const short* kh = kb + (size_t)bh * Sc * HDc;
  const short* vth = vtb + (size_t)bh * HDc * Sc;

  for (int pass = 0; pass < 2; ++pass) {
    const int qt = pass ? (31 - blockIdx.x) : blockIdx.x;
    const int q0 = qt * 64;

    short8 qf[4];
#pragma unroll
    for (int kc = 0; kc < 4; ++kc)
      qf[kc] = *(const short8*)&qh[(size_t)(q0 + w * 16 + c) * HDc + kc * 32 + g * 8];

    float mrow[4], lrow[4];
    f32x4 acc[8] = {};
#pragma unroll
    for (int r = 0; r < 4; ++r) { mrow[r] = -1e30f; lrow[r] = 0.f; }

    const int nt = qt + 1;
    int cur = 0;
    stage_kv(kh, vth, 0, Kl[0], Vl[0], w, tid);
    __syncthreads();

    for (int kvt = 0; kvt < nt; ++kvt) {
      if (kvt + 1 < nt)
        stage_kv(kh, vth, (kvt + 1) * 64, Kl[cur ^ 1], Vl[cur ^ 1], w, tid);

      f32x4 sacc[4];
#pragma unroll
      for (int kb_ = 0; kb_ < 4; ++kb_) {
        sacc[kb_] = (f32x4){0.f, 0.f, 0.f, 0.f};
#pragma unroll
        for (int kc = 0; kc < 4; ++kc) {
          short8 kf = *(const short8*)&Kl[cur][(kb_ * 16 + c) * 128 + (((kc * 4 + g) ^ (c & 7)) * 8)];
          sacc[kb_] = __builtin_amdgcn_mfma_f32_16x16x32_bf16(qf[kc], kf, sacc[kb_], 0, 0, 0);
        }
      }
      float p[4][4];
      const bool last = (kvt == qt);
      const int kv0 = kvt * 64;
#pragma unroll
      for (int kb_ = 0; kb_ < 4; ++kb_)
#pragma unroll
        for (int r = 0; r < 4; ++r) {
          float s = sacc[kb_][r] * ATTN_SCALE;
          if (last) {
            int qg = q0 + w * 16 + g * 4 + r;
            int kg = kv0 + kb_ * 16 + c;
            if (kg > qg) s = -1e30f;
          }
          p[kb_][r] = s;
        }
      float scal[4];
#pragma unroll
      for (int r = 0; r < 4; ++r) {
        float v = fmaxf(fmaxf(p[0][r], p[1][r]), fmaxf(p[2][r], p[3][r]));
        v = fmaxf(v, __shfl_xor(v, 1));
        v = fmaxf(v, __shfl_xor(v, 2));
        v = fmaxf(v, __shfl_xor(v, 4));
        v = fmaxf(v, __shfl_xor(v, 8));
        float mn = fmaxf(mrow[r], v);
        scal[r] = __expf(mrow[r] - mn);
        mrow[r] = mn;
      }
#pragma unroll
      for (int r = 0; r < 4; ++r) {
        float acc_s = 0.f;
#pragma unroll
        for (int kb_ = 0; kb_ < 4; ++kb_) {
          p[kb_][r] = __expf(p[kb_][r] - mrow[r]);
          acc_s += p[kb_][r];
        }
        acc_s += __shfl_xor(acc_s, 1);
        acc_s += __shfl_xor(acc_s, 2);
        acc_s += __shfl_xor(acc_s, 4);
        acc_s += __shfl_xor(acc_s, 8);
        lrow[r] = lrow[r] * scal[r] + acc_s;
      }
#pragma unroll
      for (int db = 0; db < 8; ++db)
#pragma unroll
        for (int r = 0; r < 4; ++r) acc[db][r] *= scal[r];
#pragma unroll
      for (int kb_ = 0; kb_ < 4; ++kb_)
#pragma unroll
        for (int r = 0; r < 4; ++r)
          Pl[w * 16 * 72 + (g * 4 + r) * 72 + kb_ * 16 + c] = f2bf(p[kb_][r]);
      short8 pa[2];
#pragma unroll
      for (int k2 = 0; k2 < 2; ++k2)
        pa[k2] = *(const short8*)&Pl[w * 16 * 72 + c * 72 + k2 * 32 + g * 8];
#pragma unroll
      for (int db = 0; db < 8; ++db)
#pragma unroll
        for (int k2 = 0; k2 < 2; ++k2) {
          short8 vf = *(const short8*)&Vl[cur][(db * 16 + c) * 64 + (((k2 * 4 + g) ^ (c & 7)) * 8)];
          acc[db] = __builtin_amdgcn_mfma_f32_16x16x32_bf16(pa[k2], vf, acc[db], 0, 0, 0);
        }
      __syncthreads();
      cur ^= 1;
    }

#pragma unroll
    for (int db = 0; db < 8; ++db)
#pragma unroll
      for (int r = 0; r < 4; ++r) {
        int qg = q0 + w * 16 + g * 4 + r;
        int d = db * 16 + c;
        float v = acc[db][r] / lrow[r];
        ob[((size_t)(b_ * Sc + qg)) * Dc + h_ * HDc + d] = f2bf(v);
      }
  }
}

extern "C" void kernel_launch(void* const* d_in, const int* in_sizes, int n_in,
                              void* d_out, int out_size, void* d_ws, size_t ws_size,
                              hipStream_t stream) {
  const float* x = (const float*)d_in[0];
  const float* wq = (const float*)d_in[1];
  const float* wk = (const float*)d_in[2];
  const float* wv = (const float*)d_in[3];
  const float* wo = (const float*)d_in[4];
  float* out = (float*)d_out;

  char* ws = (char*)d_ws;
  short* xb  = (short*)(ws + 0);              // [4096][2048] bf16 (reused as attn-out)
  short* wqb = (short*)(ws + 16777216);
  short* wkb = (short*)(ws + 25165824);
  short* wvb = (short*)(ws + 33554432);
  short* wob = (short*)(ws + 41943040);
  short* qb  = (short*)(ws + 50331648);       // [B,H,S,HD]
  short* kbf = (short*)(ws + 67108864);       // [B,H,S,HD]
  short* vtb = (short*)(ws + 83886080);       // [B,H,HD,S]  (transposed V)
  float* ct  = (float*)(ws + 100663296);      // [S][64]
  float* st  = (float*)(ws + 101187584);
  short* obuf = xb;                           // reuse x buffer for attention output

  cast_f32_bf16<<<Mc * Dc / 8 / 256, 256, 0, stream>>>(x, xb, Mc * Dc / 8);
  cast_f32_bf16<<<Dc * Dc / 8 / 256, 256, 0, stream>>>(wq, wqb, Dc * Dc / 8);
  cast_f32_bf16<<<Dc * Dc / 8 / 256, 256, 0, stream>>>(wk, wkb, Dc * Dc / 8);
  cast_f32_bf16<<<Dc * Dc / 8 / 256, 256, 0, stream>>>(wv, wvb, Dc * Dc / 8);
  cast_f32_bf16<<<Dc * Dc / 8 / 256, 256, 0, stream>>>(wo, wob, Dc * Dc / 8);
  rope_table<<<Sc * 64 / 256, 256, 0, stream>>>(ct, st);

  // QKV: N' = 3*2048 over BN=256 -> 24 x-blocks; M=4096 over BM=256 -> 16 y-blocks
  gemm8_qkv<<<dim3(24, 16), 512, 0, stream>>>(xb, wqb, wkb, wvb, qb, kbf, vtb, ct, st);

  attn_kernel<<<dim3(Sc / 128, Bc * Hc), 256, 0, stream>>>(qb, kbf, vtb, obuf);

  // Out-proj: N = 2048 -> 8 x-blocks, M -> 32 y-blocks (256 blocks, full util)
  gemm_pipe_out<<<dim3(8, 32), 512, 0, stream>>>(obuf, wob, out);
}

// Round 8
// 378.352 us; speedup vs baseline: 1.0836x; 1.0836x over previous
//
#include <hip/hip_runtime.h>
#include <stdint.h>

typedef __attribute__((ext_vector_type(4))) float f32x4;
typedef __attribute__((ext_vector_type(8))) short short8;
typedef __attribute__((ext_vector_type(4))) short s16x4;

#define DEV __device__ __forceinline__

constexpr int Bc = 2, Sc = 2048, Dc = 2048, Hc = 16, HDc = 128;
constexpr int Mc = Bc * Sc;                        // 4096 rows
constexpr float ATTN_SCALE = 0.08838834764831843f; // 1/sqrt(128)

DEV short f2bf(float f) {                          // f32 -> bf16 (RNE)
  unsigned u = __float_as_uint(f);
  unsigned r = (u + 0x7fffu + ((u >> 16) & 1u)) >> 16;
  return (short)(unsigned short)r;
}

// global -> LDS direct copy, 16B per lane. LDS dest is wave-uniform base;
// HW adds lane*16. Global source may be per-lane (enables swizzled layouts).
DEV void gload_lds16(const void* gsrc, void* ldst) {
  typedef const __attribute__((address_space(1))) void as1_cvoid;
  typedef __attribute__((address_space(3))) void as3_void;
  __builtin_amdgcn_global_load_lds((as1_cvoid*)(uintptr_t)gsrc,
                                   (as3_void*)(uint32_t)(uintptr_t)ldst,
                                   16, 0, 0);
}

__global__ void cast_f32_bf16(const float* __restrict__ in, short* __restrict__ out, int n8) {
  int i = blockIdx.x * 256 + threadIdx.x;
  if (i >= n8) return;
  f32x4 a = ((const f32x4*)in)[i * 2];
  f32x4 b = ((const f32x4*)in)[i * 2 + 1];
  short8 o;
  o[0] = f2bf(a[0]); o[1] = f2bf(a[1]); o[2] = f2bf(a[2]); o[3] = f2bf(a[3]);
  o[4] = f2bf(b[0]); o[5] = f2bf(b[1]); o[6] = f2bf(b[2]); o[7] = f2bf(b[3]);
  ((short8*)out)[i] = o;
}

__global__ void rope_table(float* __restrict__ ct, float* __restrict__ st) {
  int t = blockIdx.x * 256 + threadIdx.x;   // [0, S*64)
  int s = t >> 6, i = t & 63;
  float freq = powf(10000.0f, -(float)(2 * i) * (1.0f / 128.0f));
  float a = (float)s * freq;
  float sv, cv;
  sincosf(a, &sv, &cv);
  ct[t] = cv; st[t] = sv;
}

// ---------------------------------------------------------------------------
// Round-5 pipelined NT-GEMM (measured 126us QKV): BM=128, BN=256, BK=64,
// 512 thr (8 waves, 2M x 4N). LDS dbuf + register frag dbuf, counted
// vmcnt(6), T2 chunk-XOR swizzle, T5 setprio, T1 XCD swizzle.
// EPI=0: fused QKV (RoPE+reshape q,k; transposed V). EPI=1: out-proj f32.
// ---------------------------------------------------------------------------
template <int EPI>
__global__ __launch_bounds__(512, 2) void gemm_pipe(
    const short* __restrict__ A,
    const short* __restrict__ W0, const short* __restrict__ W1, const short* __restrict__ W2,
    short* __restrict__ qo, short* __restrict__ ko, short* __restrict__ vo,
    float* __restrict__ outf,
    const float* __restrict__ ct, const float* __restrict__ st) {
  constexpr int K = Dc, NT = K / 64;
  __shared__ short As[2][128][64];       // 32 KB
  __shared__ short Bs[2][2][128][64];    // 64 KB

  const int tid = threadIdx.x, lane = tid & 63, w = tid >> 6;
  const int g = lane >> 4, c = lane & 15;
  const int wr = w >> 2, wc = w & 3;

  const int nx = gridDim.x;
  const int nwg = nx * gridDim.y;
  const int flat = blockIdx.y * nx + blockIdx.x;
  const int swz = (flat & 7) * (nwg >> 3) + (flat >> 3);
  const int nbx = swz % nx, nby = swz / nx;

  const int m0 = nby * 128;
  const int which = (EPI == 0) ? (nbx >> 3) : 0;   // 0=q 1=k 2=v
  const int wn0 = (EPI == 0) ? ((nbx & 7) * 256) : (nbx * 256);
  const short* W = (EPI == 1) ? W0 : ((which == 0) ? W0 : (which == 1) ? W1 : W2);

  const int r1 = tid >> 3, p1 = tid & 7;
  const int psw = (p1 ^ (r1 & 7)) * 8;
  const short* gA0 = A + (size_t)(m0 + r1) * K + psw;
  const short* gA1 = gA0 + (size_t)64 * K;
  const short* gB0 = W + (size_t)(wn0 + r1) * K + psw;
  const short* gB1 = gB0 + (size_t)64 * K;
  const short* gB2 = gB0 + (size_t)128 * K;
  const short* gB3 = gB0 + (size_t)192 * K;
  char* ldsA = (char*)As + w * 1024;
  char* ldsB = (char*)Bs + w * 1024;

#define STAGE(t, db)                                        \
  do {                                                      \
    const size_t ko_ = (size_t)(t) * 64;                    \
    gload_lds16(gA0 + ko_, ldsA + (db) * 16384);            \
    gload_lds16(gA1 + ko_, ldsA + (db) * 16384 + 8192);     \
    gload_lds16(gB0 + ko_, ldsB + (db) * 32768);            \
    gload_lds16(gB1 + ko_, ldsB + (db) * 32768 + 8192);     \
    gload_lds16(gB2 + ko_, ldsB + (db) * 32768 + 16384);    \
    gload_lds16(gB3 + ko_, ldsB + (db) * 32768 + 24576);    \
  } while (0)

  f32x4 acc[4][4] = {};
  const int cx = (g ^ (c & 7)) * 16;
  const char* aBase = (const char*)As + (wr * 64 + c) * 128;
  const char* bBase = (const char*)Bs + (wc >> 1) * 16384 + ((wc & 1) * 64 + c) * 128;

  short8 afA[2][4], bfA[2][4], afB[2][4], bfB[2][4];

#define READ_FRAGS(af, bf, db)                                                        \
  do {                                                                                \
    const char* aB = aBase + (db) * 16384;                                            \
    const char* bB = bBase + (db) * 32768;                                            \
    _Pragma("unroll")                                                                 \
    for (int kk = 0; kk < 2; ++kk) {                                                  \
      const int co = cx ^ (kk * 64);                                                  \
      _Pragma("unroll")                                                               \
      for (int mi = 0; mi < 4; ++mi) af[kk][mi] = *(const short8*)(aB + mi * 2048 + co); \
      _Pragma("unroll")                                                               \
      for (int nj = 0; nj < 4; ++nj) bf[kk][nj] = *(const short8*)(bB + nj * 2048 + co); \
    }                                                                                 \
  } while (0)

#define MFMA_ALL(af, bf)                                                              \
  do {                                                                                \
    _Pragma("unroll")                                                                 \
    for (int kk = 0; kk < 2; ++kk)                                                    \
      _Pragma("unroll")                                                               \
      for (int mi = 0; mi < 4; ++mi)                                                  \
        _Pragma("unroll")                                                             \
        for (int nj = 0; nj < 4; ++nj)                                                \
          acc[mi][nj] = __builtin_amdgcn_mfma_f32_16x16x32_bf16(af[kk][mi], bf[kk][nj], acc[mi][nj], 0, 0, 0); \
  } while (0)

  STAGE(0, 0);
  STAGE(1, 1);
  asm volatile("s_waitcnt vmcnt(6)" ::: "memory");
  __builtin_amdgcn_sched_barrier(0);
  __builtin_amdgcn_s_barrier();
  READ_FRAGS(afA, bfA, 0);
  asm volatile("s_waitcnt lgkmcnt(0)" ::: "memory");
  __builtin_amdgcn_sched_barrier(0);
  __builtin_amdgcn_s_barrier();

  for (int t = 0; t < NT; t += 2) {
    if (t + 2 < NT) { STAGE(t + 2, 0); asm volatile("s_waitcnt vmcnt(6)" ::: "memory"); }
    else            { asm volatile("s_waitcnt vmcnt(0)" ::: "memory"); }
    __builtin_amdgcn_sched_barrier(0);
    __builtin_amdgcn_s_barrier();
    READ_FRAGS(afB, bfB, 1);
    __builtin_amdgcn_sched_barrier(0);
    __builtin_amdgcn_s_setprio(1);
    MFMA_ALL(afA, bfA);
    __builtin_amdgcn_s_setprio(0);
    asm volatile("s_waitcnt lgkmcnt(0)" ::: "memory");
    __builtin_amdgcn_sched_barrier(0);
    __builtin_amdgcn_s_barrier();

    if (t + 3 < NT) { STAGE(t + 3, 1); asm volatile("s_waitcnt vmcnt(6)" ::: "memory"); }
    else            { asm volatile("s_waitcnt vmcnt(0)" ::: "memory"); }
    __builtin_amdgcn_sched_barrier(0);
    __builtin_amdgcn_s_barrier();
    if (t + 2 < NT) READ_FRAGS(afA, bfA, 0);
    __builtin_amdgcn_sched_barrier(0);
    __builtin_amdgcn_s_setprio(1);
    MFMA_ALL(afB, bfB);
    __builtin_amdgcn_s_setprio(0);
    asm volatile("s_waitcnt lgkmcnt(0)" ::: "memory");
    __builtin_amdgcn_sched_barrier(0);
    __builtin_amdgcn_s_barrier();
  }
#undef STAGE
#undef READ_FRAGS
#undef MFMA_ALL

  if constexpr (EPI == 0) {
    if (which < 2) {
      short* outb = (which == 0) ? qo : ko;
#pragma unroll
      for (int mi = 0; mi < 4; ++mi)
#pragma unroll
        for (int nj = 0; nj < 4; ++nj)
#pragma unroll
          for (int r = 0; r < 4; ++r) {
            int row = m0 + wr * 64 + mi * 16 + g * 4 + r;
            int col = wn0 + wc * 64 + nj * 16 + c;
            float v = acc[mi][nj][r];
            float other = __shfl_xor(v, 1);
            int pi = (col & (HDc - 1)) >> 1;
            int sp = row & (Sc - 1);
            float cv = ct[sp * 64 + pi], sv = st[sp * 64 + pi];
            v = ((col & 1) == 0) ? (v * cv - other * sv) : (other * sv + v * cv);
            int b_ = row >> 11, sq = row & (Sc - 1);
            int h_ = col >> 7, dd = col & (HDc - 1);
            outb[((size_t)(b_ * Hc + h_) * Sc + sq) * HDc + dd] = f2bf(v);
          }
    } else {
#pragma unroll
      for (int mi = 0; mi < 4; ++mi)
#pragma unroll
        for (int nj = 0; nj < 4; ++nj) {
          int row0 = m0 + wr * 64 + mi * 16 + g * 4;
          int col = wn0 + wc * 64 + nj * 16 + c;
          int b_ = row0 >> 11, sq0 = row0 & (Sc - 1);
          int h_ = col >> 7, dd = col & (HDc - 1);
          s16x4 pk;
#pragma unroll
          for (int r = 0; r < 4; ++r) pk[r] = f2bf(acc[mi][nj][r]);
          *(s16x4*)&vo[((size_t)(b_ * Hc + h_) * HDc + dd) * Sc + sq0] = pk;
        }
    }
  } else {
#pragma unroll
    for (int mi = 0; mi < 4; ++mi)
#pragma unroll
      for (int nj = 0; nj < 4; ++nj)
#pragma unroll
        for (int r = 0; r < 4; ++r) {
          int row = m0 + wr * 64 + mi * 16 + g * 4 + r;
          int col = wn0 + wc * 64 + nj * 16 + c;
          outf[(size_t)row * Dc + col] = acc[mi][nj][r];
        }
  }
}

// ---------------------------------------------------------------------------
// Flash causal attention v2: 512 thr / 8 waves, Q-tile 128 (16 rows/wave),
// KV-tile 64, dbuf K[64x128] + V^T[128x64] (swizzled gload staging).
// Grid 256 blocks (8 j-blocks x 32 bh), bh-locality XCD mapping:
// flat%8 == bh&7 so all 8 blocks of one bh share an XCD (KV 1MB L2-local).
// Each block runs q-tiles {j, 15-j}: uniform 34 KV-iters.
// ---------------------------------------------------------------------------
DEV void stage_kv8(const short* kh, const short* vth, int kv0,
                   short* Kb, short* Vb, int w, int tid) {
#pragma unroll
  for (int i = 0; i < 2; ++i) {                 // K: 1024 chunks, 16/row
    int L = i * 512 + tid;
    int row = L >> 4, p = L & 15;
    gload_lds16(kh + (size_t)(kv0 + row) * HDc + ((p ^ (row & 7)) * 8),
                (char*)Kb + i * 8192 + w * 1024);
  }
#pragma unroll
  for (int i = 0; i < 2; ++i) {                 // V^T: 1024 chunks, 8/row
    int L = i * 512 + tid;
    int row = L >> 3, p = L & 7;
    gload_lds16(vth + (size_t)row * Sc + kv0 + ((p ^ (row & 7)) * 8),
                (char*)Vb + i * 8192 + w * 1024);
  }
}

__global__ __launch_bounds__(512) void attn_kernel(
    const short* __restrict__ qb, const short* __restrict__ kb,
    const short* __restrict__ vtb, short* __restrict__ ob) {
  __shared__ short Kl[2][64 * 128];   // 32 KB
  __shared__ short Vl[2][128 * 64];   // 32 KB
  __shared__ short Pl[8 * 16 * 72];   // 18 KB

  const int tid = threadIdx.x, lane = tid & 63, w = tid >> 6;
  const int g = lane >> 4, c = lane & 15;
  // bh-locality decode: flat%8 = bh&7 -> same-bh blocks share an XCD
  const int flat = blockIdx.y * 8 + blockIdx.x;
  const int u = flat >> 3;
  const int bh = ((u & 3) << 3) | (flat & 7);
  const int j = u >> 2;                       // 0..7
  const int b_ = bh >> 4, h_ = bh & 15;
  const short* qh = qb + (size_t)bh * Sc * HDc;
  const short* kh = kb + (size_t)bh * Sc * HDc;
  const short* vth = vtb + (size_t)bh * HDc * Sc;

  for (int pass = 0; pass < 2; ++pass) {
    const int qt = pass ? (15 - j) : j;       // q-tile of 128 rows
    const int q0 = qt * 128;

    short8 qf[4];
#pragma unroll
    for (int kc = 0; kc < 4; ++kc)
      qf[kc] = *(const short8*)&qh[(size_t)(q0 + w * 16 + c) * HDc + kc * 32 + g * 8];

    float mrow[4], lrow[4];
    f32x4 acc[8] = {};
#pragma unroll
    for (int r = 0; r < 4; ++r) { mrow[r] = -1e30f; lrow[r] = 0.f; }

    const int nt = 2 * qt + 2;
    int cur = 0;
    stage_kv8(kh, vth, 0, Kl[0], Vl[0], w, tid);
    __syncthreads();

    for (int kvt = 0; kvt < nt; ++kvt) {
      if (kvt + 1 < nt)
        stage_kv8(kh, vth, (kvt + 1) * 64, Kl[cur ^ 1], Vl[cur ^ 1], w, tid);

      // S = Q K^T (wave: 16 q-rows x 64 kv)
      f32x4 sacc[4];
#pragma unroll
      for (int kb_ = 0; kb_ < 4; ++kb_) {
        sacc[kb_] = (f32x4){0.f, 0.f, 0.f, 0.f};
#pragma unroll
        for (int kc = 0; kc < 4; ++kc) {
          short8 kf = *(const short8*)&Kl[cur][(kb_ * 16 + c) * 128 + (((kc * 4 + g) ^ (c & 7)) * 8)];
          sacc[kb_] = __builtin_amdgcn_mfma_f32_16x16x32_bf16(qf[kc], kf, sacc[kb_], 0, 0, 0);
        }
      }
      float p[4][4];
      const bool last = (kvt >= 2 * qt);      // diagonal band: mask needed
      const int kv0 = kvt * 64;
#pragma unroll
      for (int kb_ = 0; kb_ < 4; ++kb_)
#pragma unroll
        for (int r = 0; r < 4; ++r) {
          float s = sacc[kb_][r] * ATTN_SCALE;
          if (last) {
            int qg = q0 + w * 16 + g * 4 + r;
            int kg = kv0 + kb_ * 16 + c;
            if (kg > qg) s = -1e30f;
          }
          p[kb_][r] = s;
        }
      // online softmax (row r at lanes sharing g; reduce across c)
      float scal[4];
#pragma unroll
      for (int r = 0; r < 4; ++r) {
        float v = fmaxf(fmaxf(p[0][r], p[1][r]), fmaxf(p[2][r], p[3][r]));
        v = fmaxf(v, __shfl_xor(v, 1));
        v = fmaxf(v, __shfl_xor(v, 2));
        v = fmaxf(v, __shfl_xor(v, 4));
        v = fmaxf(v, __shfl_xor(v, 8));
        float mn = fmaxf(mrow[r], v);
        scal[r] = __expf(mrow[r] - mn);
        mrow[r] = mn;
      }
#pragma unroll
      for (int r = 0; r < 4; ++r) {
        float acc_s = 0.f;
#pragma unroll
        for (int kb_ = 0; kb_ < 4; ++kb_) {
          p[kb_][r] = __expf(p[kb_][r] - mrow[r]);
          acc_s += p[kb_][r];
        }
        acc_s += __shfl_xor(acc_s, 1);
        acc_s += __shfl_xor(acc_s, 2);
        acc_s += __shfl_xor(acc_s, 4);
        acc_s += __shfl_xor(acc_s, 8);
        lrow[r] = lrow[r] * scal[r] + acc_s;
      }
#pragma unroll
      for (int db = 0; db < 8; ++db)
#pragma unroll
        for (int r = 0; r < 4; ++r) acc[db][r] *= scal[r];
      // P -> per-wave LDS (bf16), read back as A-frag
#pragma unroll
      for (int kb_ = 0; kb_ < 4; ++kb_)
#pragma unroll
        for (int r = 0; r < 4; ++r)
          Pl[w * 16 * 72 + (g * 4 + r) * 72 + kb_ * 16 + c] = f2bf(p[kb_][r]);
      short8 pa[2];
#pragma unroll
      for (int k2 = 0; k2 < 2; ++k2)
        pa[k2] = *(const short8*)&Pl[w * 16 * 72 + c * 72 + k2 * 32 + g * 8];
#pragma unroll
      for (int db = 0; db < 8; ++db)
#pragma unroll
        for (int k2 = 0; k2 < 2; ++k2) {
          short8 vf = *(const short8*)&Vl[cur][(db * 16 + c) * 64 + (((k2 * 4 + g) ^ (c & 7)) * 8)];
          acc[db] = __builtin_amdgcn_mfma_f32_16x16x32_bf16(pa[k2], vf, acc[db], 0, 0, 0);
        }
      __syncthreads();
      cur ^= 1;
    }

#pragma unroll
    for (int db = 0; db < 8; ++db)
#pragma unroll
      for (int r = 0; r < 4; ++r) {
        int qg = q0 + w * 16 + g * 4 + r;
        int d = db * 16 + c;
        float v = acc[db][r] / lrow[r];
        ob[((size_t)(b_ * Sc + qg)) * Dc + h_ * HDc + d] = f2bf(v);
      }
  }
}

extern "C" void kernel_launch(void* const* d_in, const int* in_sizes, int n_in,
                              void* d_out, int out_size, void* d_ws, size_t ws_size,
                              hipStream_t stream) {
  const float* x = (const float*)d_in[0];
  const float* wq = (const float*)d_in[1];
  const float* wk = (const float*)d_in[2];
  const float* wv = (const float*)d_in[3];
  const float* wo = (const float*)d_in[4];
  float* out = (float*)d_out;

  char* ws = (char*)d_ws;
  short* xb  = (short*)(ws + 0);              // [4096][2048] bf16 (reused as attn-out)
  short* wqb = (short*)(ws + 16777216);
  short* wkb = (short*)(ws + 25165824);
  short* wvb = (short*)(ws + 33554432);
  short* wob = (short*)(ws + 41943040);
  short* qb  = (short*)(ws + 50331648);       // [B,H,S,HD]
  short* kbf = (short*)(ws + 67108864);       // [B,H,S,HD]
  short* vtb = (short*)(ws + 83886080);       // [B,H,HD,S]  (transposed V)
  float* ct  = (float*)(ws + 100663296);      // [S][64]
  float* st  = (float*)(ws + 101187584);
  short* obuf = xb;                           // reuse x buffer for attention output

  cast_f32_bf16<<<Mc * Dc / 8 / 256, 256, 0, stream>>>(x, xb, Mc * Dc / 8);
  cast_f32_bf16<<<Dc * Dc / 8 / 256, 256, 0, stream>>>(wq, wqb, Dc * Dc / 8);
  cast_f32_bf16<<<Dc * Dc / 8 / 256, 256, 0, stream>>>(wk, wkb, Dc * Dc / 8);
  cast_f32_bf16<<<Dc * Dc / 8 / 256, 256, 0, stream>>>(wv, wvb, Dc * Dc / 8);
  cast_f32_bf16<<<Dc * Dc / 8 / 256, 256, 0, stream>>>(wo, wob, Dc * Dc / 8);
  rope_table<<<Sc * 64 / 256, 256, 0, stream>>>(ct, st);

  // QKV: N' = 3*2048 over BN=256 -> 24 x-blocks; M=4096 over BM=128 -> 32 y
  gemm_pipe<0><<<dim3(24, 32), 512, 0, stream>>>(xb, wqb, wkb, wvb, qb, kbf, vtb, nullptr, ct, st);

  // attn: 8 j-blocks x 32 bh = 256 blocks, 512 threads
  attn_kernel<<<dim3(8, 32), 512, 0, stream>>>(qb, kbf, vtb, obuf);

  // Out-proj: N = 2048 -> 8 x-blocks, M -> 32 y-blocks
  gemm_pipe<1><<<dim3(8, 32), 512, 0, stream>>>(obuf, wob, nullptr, nullptr,
                                                nullptr, nullptr, nullptr, out, ct, st);
}